// Round 2
// baseline (505.875 us; speedup 1.0000x reference)
//
#include <hip/hip_runtime.h>
#include <math.h>

#define TT 512
#define BB 32
#define SS 64
#define AA 8
#define DD 32
#define EPSF 1e-6f
#define SEPS (64.0f * 1e-6f)   // reference adds EPS under the 64-term i-sum
#define TS 68                  // tile row stride (floats): 16B aligned, breaks pow2

__device__ __forceinline__ int   f2i(float x){ return __float_as_int(x); }
__device__ __forceinline__ float i2f(int x){ return __int_as_float(x); }
__device__ __forceinline__ float readlane_f(float v, int l){
  return i2f(__builtin_amdgcn_readlane(f2i(v), l));
}
// DPP add stage: ctrl/rmask must be compile-time constants -> template params
template<int CTRL, int RMASK>
__device__ __forceinline__ float dpp_add(float x){
  return x + i2f(__builtin_amdgcn_update_dpp(0, f2i(x), CTRL, RMASK, 0xf, true));
}
// full 64-lane sum via DPP (VALU only, no LDS pipe), broadcast via readlane 63
__device__ __forceinline__ float wave_sum_dpp(float x){
  x = dpp_add<0x111, 0xf>(x);  // row_shr:1
  x = dpp_add<0x112, 0xf>(x);  // row_shr:2
  x = dpp_add<0x114, 0xf>(x);  // row_shr:4
  x = dpp_add<0x118, 0xf>(x);  // row_shr:8
  x = dpp_add<0x142, 0xa>(x);  // row_bcast:15 -> rows 1,3
  x = dpp_add<0x143, 0xc>(x);  // row_bcast:31 -> rows 2,3
  return readlane_f(x, 63);
}
// shuffle helpers for the small parallel kernels (latency hidden by occupancy)
__device__ __forceinline__ float wave_sum(float v){
  #pragma unroll
  for (int m = 1; m < 64; m <<= 1) v += __shfl_xor(v, m, 64);
  return v;
}
__device__ __forceinline__ float wave_max(float v){
  #pragma unroll
  for (int m = 1; m < 64; m <<= 1) v = fmaxf(v, __shfl_xor(v, m, 64));
  return v;
}
// raw barrier: drains LDS only; global prefetch loads stay in flight
#define BARRIER() asm volatile("s_waitcnt lgkmcnt(0)\n\ts_barrier" ::: "memory")

// --- kernel 0: invvar = exp(-logv), cs[s] = sum_d logv + D*log(2pi)
__global__ void prep_kernel(const float* __restrict__ logv,
                            float* __restrict__ iv, float* __restrict__ cs){
  int gid = blockIdx.x * blockDim.x + threadIdx.x;
  if (gid < SS * DD) iv[gid] = __expf(-logv[gid]);
  if (gid < SS){
    float s = 0.f;
    #pragma unroll
    for (int d = 0; d < DD; ++d) s += logv[gid * DD + d];
    cs[gid] = s + (float)DD * 1.8378770664093453f;
  }
}

// --- kernel 1: slx[t,b,s] = lx - rowmax(lx)
__global__ __launch_bounds__(256) void logpx_kernel(
    const float* __restrict__ x, const float* __restrict__ mu,
    const float* __restrict__ iv, const float* __restrict__ cs,
    float* __restrict__ slx_out){
  const int lane = threadIdx.x & 63;
  const int w = threadIdx.x >> 6;
  const int row = blockIdx.x * 4 + w;
  const float* __restrict__ xp  = x  + row * DD;
  const float* __restrict__ mup = mu + lane * DD;
  const float* __restrict__ ivp = iv + lane * DD;
  float acc = 0.f;
  #pragma unroll
  for (int d = 0; d < DD; ++d){
    float diff = xp[d] - mup[d];
    acc = fmaf(diff * diff, ivp[d], acc);
  }
  float lx = -0.5f * (acc + cs[lane]);
  float mx = wave_max(lx);
  slx_out[row * SS + lane] = lx - mx;
}

// --- kernel T: precompute row-normalized transition tiles for t < F.
// trans[t][b][i][j] = softmax_j( w_base[i][j] + sum_k a[t,b,k] w_act[k][i][j] )
__global__ __launch_bounds__(512) void trans_kernel(
    const float* __restrict__ a, const float* __restrict__ w_base,
    const float* __restrict__ w_act, float* __restrict__ trans, int F){
  const int b  = blockIdx.x >> 4;       // 32 b  x 16 t-chunks of 32
  const int tc = blockIdx.x & 15;
  const int t0 = tc * 32;
  const int tid = threadIdx.x;
  const int i  = tid >> 3;              // row 0..63
  const int j0 = (tid & 7) * 8;         // 8 cols per thread
  __shared__ float aS[32 * 8];
  if (tid < 256)
    aS[tid] = a[(((t0 + (tid >> 3)) * BB) + b) * AA + (tid & 7)];
  float wb[8], wa[8][8];
  #pragma unroll
  for (int jj = 0; jj < 8; ++jj){
    wb[jj] = w_base[i * SS + j0 + jj];
    #pragma unroll
    for (int k = 0; k < 8; ++k)
      wa[k][jj] = w_act[(k * SS + i) * SS + j0 + jj];
  }
  __syncthreads();
  int rem = F - t0;
  const int nt = (rem < 0) ? 0 : (rem < 32 ? rem : 32);
  for (int tt = 0; tt < nt; ++tt){
    float aa[8];
    #pragma unroll
    for (int k = 0; k < 8; ++k) aa[k] = aS[tt * 8 + k];
    float ev[8]; float rs = 0.f;
    #pragma unroll
    for (int jj = 0; jj < 8; ++jj){
      float u = wb[jj];
      #pragma unroll
      for (int k = 0; k < 8; ++k) u = fmaf(aa[k], wa[k][jj], u);
      ev[jj] = __expf(u); rs += ev[jj];
    }
    // full row sum: 8 threads (lanes differing in bits 0..2) share row i
    rs += __shfl_xor(rs, 1, 64);
    rs += __shfl_xor(rs, 2, 64);
    rs += __shfl_xor(rs, 4, 64);
    float rinv = __builtin_amdgcn_rcpf(rs);
    float* __restrict__ op = trans + ((size_t)(t0 + tt) * BB + b) * (SS * SS)
                           + i * SS + j0;
    *(float4*)op       = make_float4(ev[0]*rinv, ev[1]*rinv, ev[2]*rinv, ev[3]*rinv);
    *(float4*)(op + 4) = make_float4(ev[4]*rinv, ev[5]*rinv, ev[6]*rinv, ev[7]*rinv);
  }
}

// --- kernel 2: fused pipelined scans. blocks [0,B): fwd; [B,2B): bwd.
// 768 thr = 12 waves: waves 0-3 consumers, waves 4-11 producers.
// Producers STREAM precomputed tiles for t < F (4x dwordx4 + LDS writes,
// 3-deep register prefetch; rsp marker 0.125 so rowsum=1) and GENERATE
// tiles for t >= F in-block (identical math to the proven fallback).
// F==0 reproduces the previous 403us kernel's behavior exactly.
#define LOADW() do{ \
  _Pragma("unroll") \
  for (int jj = 0; jj < 8; ++jj){ \
    wb[jj] = w_base[lane * SS + jb + jj]; \
    _Pragma("unroll") \
    for (int k = 0; k < 8; ++k) \
      wa[k][jj] = w_act[(k * SS + lane) * SS + jb + jj]; \
  } \
}while(0)

#define GENT(SLOT) do{ \
  float ev[8]; float racc = 0.f; \
  _Pragma("unroll") \
  for (int jj = 0; jj < 8; ++jj){ \
    float u = wb[jj]; \
    _Pragma("unroll") \
    for (int k = 0; k < 8; ++k) u = fmaf(aa[k], wa[k][jj], u); \
    ev[jj] = __expf(u); racc += ev[jj]; \
  } \
  *(float4*)&tile[SLOT][lane * TS + jb]     = make_float4(ev[0],ev[1],ev[2],ev[3]); \
  *(float4*)&tile[SLOT][lane * TS + jb + 4] = make_float4(ev[4],ev[5],ev[6],ev[7]); \
  rsp[SLOT][pw][lane] = racc; \
}while(0)

__global__ __launch_bounds__(768) void scan_hybrid_kernel(
    const float* __restrict__ slx, const float* __restrict__ mask,
    const float* __restrict__ il, const float* __restrict__ a,
    const float* __restrict__ w_base, const float* __restrict__ w_act,
    const float* __restrict__ trans, int F,
    float* __restrict__ alpha, float* __restrict__ log_beta){
  const int lane = threadIdx.x & 63;
  const int w    = threadIdx.x >> 6;
  const bool is_fwd = (blockIdx.x < BB);
  const int b = is_fwd ? blockIdx.x : (blockIdx.x - BB);

  __shared__ __align__(16) float tile[3][SS * TS];  // tiles, [i][j]
  __shared__ float rsp[3][8][SS];                   // row-sum partials (1/8 if streamed)
  __shared__ float fpart[2][4][SS];                 // consumer matvec partials
  __shared__ __align__(16) float aLDS[TT * AA];     // a[:, b, :] staged
  __shared__ float mLDS[TT];                        // mask[:, b] staged

  for (int idx = threadIdx.x; idx < TT * AA; idx += 768){
    int t = idx >> 3, k = idx & 7;
    aLDS[idx] = a[(t * BB + b) * AA + k];
  }
  for (int idx = threadIdx.x; idx < TT; idx += 768)
    mLDS[idx] = mask[idx * BB + b];

  if (w >= 4){
    // ======================= PRODUCERS =======================
    const int pw = w - 4;
    const int jb = pw * 8;
    // streaming layout: lane-global float index g in [0,4096)
    const int g      = pw * 512 + lane * 8;
    const int ldsoff = (g >> 6) * TS + (g & 63);
    const size_t tstride = (size_t)BB * SS * SS;
    const float* __restrict__ gb = trans + (size_t)b * (SS * SS) + g;

    float wb[8], wa[8][8];
    float aa[8], aan[8];
    const int t0 = is_fwd ? 0 : (TT - 2);

    if (t0 >= F){
      // prologue GEN: weights + a[t0] from global (pre-barrier)
      LOADW();
      const float* __restrict__ ap = a + ((size_t)t0 * BB + b) * AA;
      #pragma unroll
      for (int k = 0; k < 8; ++k) aa[k] = ap[k];
      GENT(0);
    } else {
      // prologue STREAM tile t0
      const float4* gp = (const float4*)(gb + (size_t)t0 * tstride);
      float4 c0 = gp[0], c1 = gp[1];
      float* tp = &tile[0][ldsoff];
      *(float4*)tp = c0; *(float4*)(tp + 4) = c1;
      rsp[0][pw][lane] = 0.125f;
    }
    BARRIER();
    int tw = 1, s = 0;

    if (is_fwd){
      // ---- stream phase: tiles 1..F-1 (iterations s = 0..F-2)
      if (F >= 2){
        float4 A0, A1, B0, B1, C0, C1;
        { const float4* p = (const float4*)(gb + 1 * tstride); A0 = p[0]; A1 = p[1]; }
        if (F >= 3){ const float4* p = (const float4*)(gb + 2 * tstride); B0 = p[0]; B1 = p[1]; }
        if (F >= 4){ const float4* p = (const float4*)(gb + 3 * tstride); C0 = p[0]; C1 = p[1]; }
        int tnext = 4, par = 0;
        for (int ti = 1; ti <= F - 1; ++ti, ++s){
          float* tp = &tile[tw][ldsoff];
          if (par == 0){
            *(float4*)tp = A0; *(float4*)(tp + 4) = A1;
            if (tnext <= F - 1){ const float4* p = (const float4*)(gb + (size_t)tnext * tstride); A0 = p[0]; A1 = p[1]; ++tnext; }
          } else if (par == 1){
            *(float4*)tp = B0; *(float4*)(tp + 4) = B1;
            if (tnext <= F - 1){ const float4* p = (const float4*)(gb + (size_t)tnext * tstride); B0 = p[0]; B1 = p[1]; ++tnext; }
          } else {
            *(float4*)tp = C0; *(float4*)(tp + 4) = C1;
            if (tnext <= F - 1){ const float4* p = (const float4*)(gb + (size_t)tnext * tstride); C0 = p[0]; C1 = p[1]; ++tnext; }
          }
          par = (par == 2) ? 0 : par + 1;
          rsp[tw][pw][lane] = 0.125f;
          tw = (tw == 2) ? 0 : tw + 1;
          BARRIER();
        }
      }
      // ---- gen phase: tiles max(F,1)..TT-2 (iterations s = F-1..TT-3)
      if (s <= TT - 3){
        if (t0 < F) LOADW();              // not loaded in prologue
        const int tg0 = s + 1;
        #pragma unroll
        for (int k = 0; k < 8; ++k) aa[k] = aLDS[tg0 * AA + k];
        for (; s <= TT - 3; ++s){
          const int tgi = s + 1;
          if (tgi + 1 <= TT - 2){
            #pragma unroll
            for (int k = 0; k < 8; ++k) aan[k] = aLDS[(tgi + 1) * AA + k];
          }
          GENT(tw);
          #pragma unroll
          for (int k = 0; k < 8; ++k) aa[k] = aan[k];
          tw = (tw == 2) ? 0 : tw + 1;
          BARRIER();
        }
      }
    } else {
      // ---- gen phase first: tiles TT-3-s while >= F
      if (s <= TT - 3 && (TT - 3 - s) >= F){
        // weights already loaded: gen phase nonempty => t0 = TT-2 > F => prologue was GEN
        const int tg0 = TT - 3;
        #pragma unroll
        for (int k = 0; k < 8; ++k) aa[k] = aLDS[tg0 * AA + k];
        for (; s <= TT - 3 && (TT - 3 - s) >= F; ++s){
          const int tgi = TT - 3 - s;
          if (tgi > F){
            #pragma unroll
            for (int k = 0; k < 8; ++k) aan[k] = aLDS[(tgi - 1) * AA + k];
          }
          GENT(tw);
          #pragma unroll
          for (int k = 0; k < 8; ++k) aa[k] = aan[k];
          tw = (tw == 2) ? 0 : tw + 1;
          BARRIER();
        }
      }
      // ---- stream phase: descending tiles (TT-3-s)..0, all < F
      if (s <= TT - 3){
        const int tc0 = TT - 3 - s;
        float4 A0, A1, B0, B1, C0, C1;
        { const float4* p = (const float4*)(gb + (size_t)tc0 * tstride); A0 = p[0]; A1 = p[1]; }
        if (tc0 - 1 >= 0){ const float4* p = (const float4*)(gb + (size_t)(tc0 - 1) * tstride); B0 = p[0]; B1 = p[1]; }
        if (tc0 - 2 >= 0){ const float4* p = (const float4*)(gb + (size_t)(tc0 - 2) * tstride); C0 = p[0]; C1 = p[1]; }
        int tnext = tc0 - 3, par = 0;
        for (; s <= TT - 3; ++s){
          float* tp = &tile[tw][ldsoff];
          if (par == 0){
            *(float4*)tp = A0; *(float4*)(tp + 4) = A1;
            if (tnext >= 0){ const float4* p = (const float4*)(gb + (size_t)tnext * tstride); A0 = p[0]; A1 = p[1]; --tnext; }
          } else if (par == 1){
            *(float4*)tp = B0; *(float4*)(tp + 4) = B1;
            if (tnext >= 0){ const float4* p = (const float4*)(gb + (size_t)tnext * tstride); B0 = p[0]; B1 = p[1]; --tnext; }
          } else {
            *(float4*)tp = C0; *(float4*)(tp + 4) = C1;
            if (tnext >= 0){ const float4* p = (const float4*)(gb + (size_t)tnext * tstride); C0 = p[0]; C1 = p[1]; --tnext; }
          }
          par = (par == 2) ? 0 : par + 1;
          rsp[tw][pw][lane] = 0.125f;
          tw = (tw == 2) ? 0 : tw + 1;
          BARRIER();
        }
      }
    }
    // tail: final consumer iteration produces nothing
    for (; s <= TT - 2; ++s) BARRIER();
  } else if (is_fwd){
    // ==================== FORWARD CONSUMERS ====================
    const int wb16 = __builtin_amdgcn_readfirstlane(w * 16);
    float u = __expf(slx[b * SS + lane] + il[lane]);     // unnormalized alpha_0
    float c = __builtin_amdgcn_rcpf(wave_sum_dpp(u));
    if (w == 0) alpha[b * SS + lane] = u * c;
    float slxn = slx[(BB + b) * SS + lane];              // slx[t=1]
    float elxc = 0.f;
    BARRIER();
    int ts = 0;
    for (int s = 0; s < TT - 1; ++s){
      if (s > 0){
        const int fs = (s - 1) & 1;
        float S = (fpart[fs][0][lane] + fpart[fs][1][lane])
                + (fpart[fs][2][lane] + fpart[fs][3][lane]);
        u = elxc * fmaf(c, S, SEPS);                     // alpha_s (unnormalized)
        c = __builtin_amdgcn_rcpf(wave_sum_dpp(u));      // off critical path (DPP)
        if (w == 0) alpha[(s * BB + b) * SS + lane] = u * c;
      }
      float rs = ((rsp[ts][0][lane] + rsp[ts][1][lane]) + (rsp[ts][2][lane] + rsp[ts][3][lane]))
               + ((rsp[ts][4][lane] + rsp[ts][5][lane]) + (rsp[ts][6][lane] + rsp[ts][7][lane]));
      float va = u * __builtin_amdgcn_rcpf(rs);          // u_i / rowsum_i (lane = i)
      const float* __restrict__ tp = &tile[ts][0];
      float a0 = 0.f, a1 = 0.f, a2 = 0.f, a3 = 0.f;
      #pragma unroll
      for (int r = 0; r < 16; r += 4){
        a0 = fmaf(readlane_f(va, wb16 + r    ), tp[(wb16 + r    ) * TS + lane], a0);
        a1 = fmaf(readlane_f(va, wb16 + r + 1), tp[(wb16 + r + 1) * TS + lane], a1);
        a2 = fmaf(readlane_f(va, wb16 + r + 2), tp[(wb16 + r + 2) * TS + lane], a2);
        a3 = fmaf(readlane_f(va, wb16 + r + 3), tp[(wb16 + r + 3) * TS + lane], a3);
      }
      fpart[s & 1][w][lane] = (a0 + a1) + (a2 + a3);
      elxc = __expf(slxn);                               // for step s+1, off path
      if (s + 2 <= TT - 1) slxn = slx[((s + 2) * BB + b) * SS + lane];
      ts = (ts == 2) ? 0 : ts + 1;
      BARRIER();
    }
    { // epilogue: alpha_{T-1}
      const int fs = (TT - 2) & 1;
      float S = (fpart[fs][0][lane] + fpart[fs][1][lane])
              + (fpart[fs][2][lane] + fpart[fs][3][lane]);
      u = elxc * fmaf(c, S, SEPS);
      c = __builtin_amdgcn_rcpf(wave_sum_dpp(u));
      if (w == 0) alpha[((TT - 1) * BB + b) * SS + lane] = u * c;
    }
  } else {
    // ==================== BACKWARD CONSUMERS ====================
    // breg kept in relative form (per-(t,b) shift drops in the q_z softmax);
    // renormalized by W each step so all values stay in [ln EPS, ~0].
    const int wb16 = __builtin_amdgcn_readfirstlane(w * 16);
    float breg = 0.f, rWc = 1.f;
    if (w == 0) log_beta[((TT - 1) * BB + b) * SS + lane] = 0.f;
    float slxc = slx[((TT - 1) * BB + b) * SS + lane];
    float mprev = 1.f;
    BARRIER();
    int ts = 0, pts = 2;
    for (int s = 0; s < TT - 1; ++s){
      if (s > 0){
        const int fs = (s - 1) & 1;
        float eh = (fpart[fs][0][lane] + fpart[fs][1][lane])
                 + (fpart[fs][2][lane] + fpart[fs][3][lane]);
        float rsv = ((rsp[pts][0][lane] + rsp[pts][1][lane]) + (rsp[pts][2][lane] + rsp[pts][3][lane]))
                  + ((rsp[pts][4][lane] + rsp[pts][5][lane]) + (rsp[pts][6][lane] + rsp[pts][7][lane]));
        // v = log( sum_j (tr_ij/rowsum_i) * wgt_j / W + EPS )  (shift-relative LSE)
        float v = __logf(fmaf(eh * __builtin_amdgcn_rcpf(rsv), rWc, EPSF));
        breg = (mprev == 1.0f) ? v : 0.0f;
        if (w == 0) log_beta[((TT - 1 - s) * BB + b) * SS + lane] = breg;
      }
      float wgt = __expf(slxc + breg);                   // lane = j
      float W = wave_sum_dpp(wgt);                       // overlaps matvec (VALU)
      rWc = __builtin_amdgcn_rcpf(W);                    // consumed next iter
      const float* __restrict__ tp = &tile[ts][lane * TS + wb16];
      float4 e0 = *(const float4*)(tp);
      float4 e1 = *(const float4*)(tp + 4);
      float4 e2 = *(const float4*)(tp + 8);
      float4 e3 = *(const float4*)(tp + 12);
      float a0 = 0.f, a1 = 0.f, a2 = 0.f, a3 = 0.f;
      a0 = fmaf(readlane_f(wgt, wb16 + 0),  e0.x, a0);
      a1 = fmaf(readlane_f(wgt, wb16 + 1),  e0.y, a1);
      a2 = fmaf(readlane_f(wgt, wb16 + 2),  e0.z, a2);
      a3 = fmaf(readlane_f(wgt, wb16 + 3),  e0.w, a3);
      a0 = fmaf(readlane_f(wgt, wb16 + 4),  e1.x, a0);
      a1 = fmaf(readlane_f(wgt, wb16 + 5),  e1.y, a1);
      a2 = fmaf(readlane_f(wgt, wb16 + 6),  e1.z, a2);
      a3 = fmaf(readlane_f(wgt, wb16 + 7),  e1.w, a3);
      a0 = fmaf(readlane_f(wgt, wb16 + 8),  e2.x, a0);
      a1 = fmaf(readlane_f(wgt, wb16 + 9),  e2.y, a1);
      a2 = fmaf(readlane_f(wgt, wb16 + 10), e2.z, a2);
      a3 = fmaf(readlane_f(wgt, wb16 + 11), e2.w, a3);
      a0 = fmaf(readlane_f(wgt, wb16 + 12), e3.x, a0);
      a1 = fmaf(readlane_f(wgt, wb16 + 13), e3.y, a1);
      a2 = fmaf(readlane_f(wgt, wb16 + 14), e3.z, a2);
      a3 = fmaf(readlane_f(wgt, wb16 + 15), e3.w, a3);
      fpart[s & 1][w][lane] = (a0 + a1) + (a2 + a3);
      mprev = mLDS[TT - 1 - s];
      if (s <= TT - 3) slxc = slx[((TT - 2 - s) * BB + b) * SS + lane];
      pts = ts; ts = (ts == 2) ? 0 : ts + 1;
      BARRIER();
    }
    { // epilogue: breg_0
      const int fs = (TT - 2) & 1;
      float eh = (fpart[fs][0][lane] + fpart[fs][1][lane])
               + (fpart[fs][2][lane] + fpart[fs][3][lane]);
      float rsv = ((rsp[pts][0][lane] + rsp[pts][1][lane]) + (rsp[pts][2][lane] + rsp[pts][3][lane]))
                + ((rsp[pts][4][lane] + rsp[pts][5][lane]) + (rsp[pts][6][lane] + rsp[pts][7][lane]));
      float v = __logf(fmaf(eh * __builtin_amdgcn_rcpf(rsv), rWc, EPSF));
      breg = (mprev == 1.0f) ? v : 0.0f;
      if (w == 0) log_beta[b * SS + lane] = breg;
    }
  }
}

// --- kernel 3: q_z = softmax(log(alpha+EPS) + log_beta) over states
__global__ __launch_bounds__(256) void qz_kernel(
    const float* __restrict__ alpha, const float* __restrict__ log_beta,
    float* __restrict__ out){
  const int lane = threadIdx.x & 63;
  const int w = threadIdx.x >> 6;
  const int row = blockIdx.x * 4 + w;
  float v = __logf(alpha[row * SS + lane] + EPSF) + log_beta[row * SS + lane];
  float mx = wave_max(v);
  float e = __expf(v - mx);
  float sm = wave_sum(e);
  out[row * SS + lane] = e * __builtin_amdgcn_rcpf(sm);
}

extern "C" void kernel_launch(void* const* d_in, const int* in_sizes, int n_in,
                              void* d_out, int out_size, void* d_ws, size_t ws_size,
                              hipStream_t stream){
  const float* x      = (const float*)d_in[0];
  const float* a      = (const float*)d_in[1];
  const float* mask   = (const float*)d_in[2];
  const float* mu     = (const float*)d_in[3];
  const float* logv   = (const float*)d_in[4];
  const float* il     = (const float*)d_in[5];
  const float* w_base = (const float*)d_in[6];
  const float* w_act  = (const float*)d_in[7];
  float* out = (float*)d_out;

  float* ws = (float*)d_ws;
  const size_t TBS = (size_t)TT * BB * SS;
  float* iv       = ws;               // 2048 (+ cs, padded to 4096)
  float* cs       = ws + 2048;
  float* slx      = ws + 4096;        // TBS
  float* alpha    = slx + TBS;        // TBS
  float* log_beta = alpha + TBS;      // TBS
  float* trans    = log_beta + TBS;   // F tiles of BB*SS*SS floats

  // Adaptive precompute depth: as many of the 511 transition tiles as the
  // workspace can hold (each t-slice = BB*SS*SS floats = 512 KB).
  const long long base_floats = 4096 + 3 * (long long)TBS;
  const long long tile_floats = (long long)BB * SS * SS;
  long long availf = (long long)(ws_size / 4) - base_floats;
  int F = 0;
  if (availf > 0){
    long long f = availf / tile_floats;
    F = (f > (TT - 1)) ? (TT - 1) : (int)f;
  }
  if (F < 8) F = 0;   // not worth the stream prologue edge cases

  prep_kernel<<<8, 256, 0, stream>>>(logv, iv, cs);
  logpx_kernel<<<TT * BB / 4, 256, 0, stream>>>(x, mu, iv, cs, slx);
  if (F > 0)
    trans_kernel<<<512, 512, 0, stream>>>(a, w_base, w_act, trans, F);
  scan_hybrid_kernel<<<2 * BB, 768, 0, stream>>>(slx, mask, il, a, w_base, w_act,
                                                 trans, F, alpha, log_beta);
  qz_kernel<<<TT * BB / 4, 256, 0, stream>>>(alpha, log_beta, out);
}

// Round 3
// 424.775 us; speedup vs baseline: 1.1909x; 1.1909x over previous
//
#include <hip/hip_runtime.h>
#include <hip/hip_fp16.h>
#include <math.h>

#define TT 512
#define BB 32
#define SS 64
#define AA 8
#define DD 32
#define EPSF 1e-6f
#define SEPS (64.0f * 1e-6f)   // reference adds EPS under the 64-term i-sum
#define TS 68                  // tile row stride (floats): 16B aligned, breaks pow2

__device__ __forceinline__ int   f2i(float x){ return __float_as_int(x); }
__device__ __forceinline__ float i2f(int x){ return __int_as_float(x); }
__device__ __forceinline__ float readlane_f(float v, int l){
  return i2f(__builtin_amdgcn_readlane(f2i(v), l));
}
// DPP add stage: ctrl/rmask must be compile-time constants -> template params
template<int CTRL, int RMASK>
__device__ __forceinline__ float dpp_add(float x){
  return x + i2f(__builtin_amdgcn_update_dpp(0, f2i(x), CTRL, RMASK, 0xf, true));
}
// full 64-lane sum via DPP (VALU only, no LDS pipe), broadcast via readlane 63
__device__ __forceinline__ float wave_sum_dpp(float x){
  x = dpp_add<0x111, 0xf>(x);  // row_shr:1
  x = dpp_add<0x112, 0xf>(x);  // row_shr:2
  x = dpp_add<0x114, 0xf>(x);  // row_shr:4
  x = dpp_add<0x118, 0xf>(x);  // row_shr:8
  x = dpp_add<0x142, 0xa>(x);  // row_bcast:15 -> rows 1,3
  x = dpp_add<0x143, 0xc>(x);  // row_bcast:31 -> rows 2,3
  return readlane_f(x, 63);
}
// shuffle helpers for the small parallel kernels (latency hidden by occupancy)
__device__ __forceinline__ float wave_sum(float v){
  #pragma unroll
  for (int m = 1; m < 64; m <<= 1) v += __shfl_xor(v, m, 64);
  return v;
}
__device__ __forceinline__ float wave_max(float v){
  #pragma unroll
  for (int m = 1; m < 64; m <<= 1) v = fmaxf(v, __shfl_xor(v, m, 64));
  return v;
}
// raw barrier: drains LDS only; global prefetch loads stay in flight
#define BARRIER() asm volatile("s_waitcnt lgkmcnt(0)\n\ts_barrier" ::: "memory")

// fp16 pack/unpack helpers (RN rounding)
__device__ __forceinline__ unsigned pk2(float a, float b){
  return (unsigned)__half_as_ushort(__float2half_rn(a))
       | ((unsigned)__half_as_ushort(__float2half_rn(b)) << 16);
}
__device__ __forceinline__ float uplo(unsigned u){
  return __half2float(__ushort_as_half((unsigned short)(u & 0xffffu)));
}
__device__ __forceinline__ float uphi(unsigned u){
  return __half2float(__ushort_as_half((unsigned short)(u >> 16)));
}

// --- kernel 0: invvar = exp(-logv), cs[s] = sum_d logv + D*log(2pi)
__global__ void prep_kernel(const float* __restrict__ logv,
                            float* __restrict__ iv, float* __restrict__ cs){
  int gid = blockIdx.x * blockDim.x + threadIdx.x;
  if (gid < SS * DD) iv[gid] = __expf(-logv[gid]);
  if (gid < SS){
    float s = 0.f;
    #pragma unroll
    for (int d = 0; d < DD; ++d) s += logv[gid * DD + d];
    cs[gid] = s + (float)DD * 1.8378770664093453f;
  }
}

// --- kernel 1: slx[t,b,s] = lx - rowmax(lx)
__global__ __launch_bounds__(256) void logpx_kernel(
    const float* __restrict__ x, const float* __restrict__ mu,
    const float* __restrict__ iv, const float* __restrict__ cs,
    float* __restrict__ slx_out){
  const int lane = threadIdx.x & 63;
  const int w = threadIdx.x >> 6;
  const int row = blockIdx.x * 4 + w;
  const float* __restrict__ xp  = x  + row * DD;
  const float* __restrict__ mup = mu + lane * DD;
  const float* __restrict__ ivp = iv + lane * DD;
  float acc = 0.f;
  #pragma unroll
  for (int d = 0; d < DD; ++d){
    float diff = xp[d] - mup[d];
    acc = fmaf(diff * diff, ivp[d], acc);
  }
  float lx = -0.5f * (acc + cs[lane]);
  float mx = wave_max(lx);
  slx_out[row * SS + lane] = lx - mx;
}

// --- kernel T: precompute row-normalized transition tiles for t < F, fp16.
// trans[t][b][i][j] = softmax_j( w_base[i][j] + sum_k a[t,b,k] w_act[k][i][j] )
// fp16 total = 134 MB -> fully Infinity-Cache resident.
__global__ __launch_bounds__(512) void trans_kernel(
    const float* __restrict__ a, const float* __restrict__ w_base,
    const float* __restrict__ w_act, unsigned short* __restrict__ trans, int F){
  const int b  = blockIdx.x >> 4;       // 32 b  x 16 t-chunks of 32
  const int tc = blockIdx.x & 15;
  const int t0 = tc * 32;
  const int tid = threadIdx.x;
  const int i  = tid >> 3;              // row 0..63
  const int j0 = (tid & 7) * 8;         // 8 cols per thread
  __shared__ float aS[32 * 8];
  if (tid < 256)
    aS[tid] = a[(((t0 + (tid >> 3)) * BB) + b) * AA + (tid & 7)];
  float wb[8], wa[8][8];
  #pragma unroll
  for (int jj = 0; jj < 8; ++jj){
    wb[jj] = w_base[i * SS + j0 + jj];
    #pragma unroll
    for (int k = 0; k < 8; ++k)
      wa[k][jj] = w_act[(k * SS + i) * SS + j0 + jj];
  }
  __syncthreads();
  int rem = F - t0;
  const int nt = (rem < 0) ? 0 : (rem < 32 ? rem : 32);
  for (int tt = 0; tt < nt; ++tt){
    float aa[8];
    #pragma unroll
    for (int k = 0; k < 8; ++k) aa[k] = aS[tt * 8 + k];
    float ev[8]; float rs = 0.f;
    #pragma unroll
    for (int jj = 0; jj < 8; ++jj){
      float u = wb[jj];
      #pragma unroll
      for (int k = 0; k < 8; ++k) u = fmaf(aa[k], wa[k][jj], u);
      ev[jj] = __expf(u); rs += ev[jj];
    }
    // full row sum: 8 threads (lanes differing in bits 0..2) share row i
    rs += __shfl_xor(rs, 1, 64);
    rs += __shfl_xor(rs, 2, 64);
    rs += __shfl_xor(rs, 4, 64);
    float rinv = __builtin_amdgcn_rcpf(rs);
    unsigned short* __restrict__ op = trans
        + ((size_t)(t0 + tt) * BB + b) * (SS * SS) + i * SS + j0;
    uint4 o;
    o.x = pk2(ev[0]*rinv, ev[1]*rinv);
    o.y = pk2(ev[2]*rinv, ev[3]*rinv);
    o.z = pk2(ev[4]*rinv, ev[5]*rinv);
    o.w = pk2(ev[6]*rinv, ev[7]*rinv);
    *(uint4*)op = o;
  }
}

// --- kernel 2: fused pipelined scans. blocks [0,B): fwd; [B,2B): bwd.
// 768 thr = 12 waves: waves 0-3 consumers, waves 4-11 producers.
// Producers STREAM fp16 tiles for t < F (one dwordx4 of 8 halves per lane,
// 3-deep register prefetch; unpacked to fp32 in LDS) and GENERATE tiles
// for t >= F in-block. Streamed tiles are pre-normalized: consumers skip
// the row-sum LDS reads for them. F==0 == the proven 403us kernel.
#define LOADW() do{ \
  _Pragma("unroll") \
  for (int jj = 0; jj < 8; ++jj){ \
    wb[jj] = w_base[lane * SS + jb + jj]; \
    _Pragma("unroll") \
    for (int k = 0; k < 8; ++k) \
      wa[k][jj] = w_act[(k * SS + lane) * SS + jb + jj]; \
  } \
}while(0)

#define GENT(SLOT) do{ \
  float ev[8]; float racc = 0.f; \
  _Pragma("unroll") \
  for (int jj = 0; jj < 8; ++jj){ \
    float u = wb[jj]; \
    _Pragma("unroll") \
    for (int k = 0; k < 8; ++k) u = fmaf(aa[k], wa[k][jj], u); \
    ev[jj] = __expf(u); racc += ev[jj]; \
  } \
  *(float4*)&tile[SLOT][lane * TS + jb]     = make_float4(ev[0],ev[1],ev[2],ev[3]); \
  *(float4*)&tile[SLOT][lane * TS + jb + 4] = make_float4(ev[4],ev[5],ev[6],ev[7]); \
  rsp[SLOT][pw][lane] = racc; \
}while(0)

#define STORE_H8(SLOT, P) do{ \
  float* tp = &tile[SLOT][ldsoff]; \
  *(float4*)tp       = make_float4(uplo(P.x), uphi(P.x), uplo(P.y), uphi(P.y)); \
  *(float4*)(tp + 4) = make_float4(uplo(P.z), uphi(P.z), uplo(P.w), uphi(P.w)); \
}while(0)

__global__ __launch_bounds__(768) void scan_hybrid_kernel(
    const float* __restrict__ slx, const float* __restrict__ mask,
    const float* __restrict__ il, const float* __restrict__ a,
    const float* __restrict__ w_base, const float* __restrict__ w_act,
    const unsigned short* __restrict__ trans, int F,
    float* __restrict__ alpha, float* __restrict__ log_beta){
  const int lane = threadIdx.x & 63;
  const int w    = threadIdx.x >> 6;
  const bool is_fwd = (blockIdx.x < BB);
  const int b = is_fwd ? blockIdx.x : (blockIdx.x - BB);

  __shared__ __align__(16) float tile[3][SS * TS];  // tiles (fp32), [i][j]
  __shared__ float rsp[3][8][SS];                   // row-sum partials (gen only)
  __shared__ float fpart[2][4][SS];                 // consumer matvec partials
  __shared__ __align__(16) float aLDS[TT * AA];     // a[:, b, :] staged
  __shared__ float mLDS[TT];                        // mask[:, b] staged

  for (int idx = threadIdx.x; idx < TT * AA; idx += 768){
    int t = idx >> 3, k = idx & 7;
    aLDS[idx] = a[(t * BB + b) * AA + k];
  }
  for (int idx = threadIdx.x; idx < TT; idx += 768)
    mLDS[idx] = mask[idx * BB + b];

  if (w >= 4){
    // ======================= PRODUCERS =======================
    const int pw = w - 4;
    const int jb = pw * 8;
    // streaming layout: lane-global half index g in [0,4096)
    const int g      = pw * 512 + lane * 8;
    const int ldsoff = (g >> 6) * TS + (g & 63);
    const size_t tsh = (size_t)BB * SS * SS;        // halves per t-slice
    const unsigned short* __restrict__ gbh = trans + (size_t)b * (SS * SS) + g;

    float wb[8], wa[8][8];
    float aa[8], aan[8];
    const int t0 = is_fwd ? 0 : (TT - 2);

    if (t0 >= F){
      // prologue GEN: weights + a[t0] from global (pre-barrier)
      LOADW();
      const float* __restrict__ ap = a + ((size_t)t0 * BB + b) * AA;
      #pragma unroll
      for (int k = 0; k < 8; ++k) aa[k] = ap[k];
      GENT(0);
    } else {
      // prologue STREAM tile t0
      uint4 P = *(const uint4*)(gbh + (size_t)t0 * tsh);
      STORE_H8(0, P);
    }
    BARRIER();
    int tw = 1, s = 0;

    if (is_fwd){
      // ---- stream phase: tiles 1..F-1 (iterations s = 0..F-2)
      if (F >= 2){
        uint4 A, B, C;
        A = *(const uint4*)(gbh + 1 * tsh);
        if (F >= 3) B = *(const uint4*)(gbh + 2 * tsh);
        if (F >= 4) C = *(const uint4*)(gbh + 3 * tsh);
        int tnext = 4, par = 0;
        for (int ti = 1; ti <= F - 1; ++ti, ++s){
          if (par == 0){
            STORE_H8(tw, A);
            if (tnext <= F - 1){ A = *(const uint4*)(gbh + (size_t)tnext * tsh); ++tnext; }
          } else if (par == 1){
            STORE_H8(tw, B);
            if (tnext <= F - 1){ B = *(const uint4*)(gbh + (size_t)tnext * tsh); ++tnext; }
          } else {
            STORE_H8(tw, C);
            if (tnext <= F - 1){ C = *(const uint4*)(gbh + (size_t)tnext * tsh); ++tnext; }
          }
          par = (par == 2) ? 0 : par + 1;
          tw = (tw == 2) ? 0 : tw + 1;
          BARRIER();
        }
      }
      // ---- gen phase: tiles max(F,1)..TT-2 (iterations s = F-1..TT-3)
      if (s <= TT - 3){
        if (t0 < F) LOADW();              // not loaded in prologue
        const int tg0 = s + 1;
        #pragma unroll
        for (int k = 0; k < 8; ++k) aa[k] = aLDS[tg0 * AA + k];
        for (; s <= TT - 3; ++s){
          const int tgi = s + 1;
          if (tgi + 1 <= TT - 2){
            #pragma unroll
            for (int k = 0; k < 8; ++k) aan[k] = aLDS[(tgi + 1) * AA + k];
          }
          GENT(tw);
          #pragma unroll
          for (int k = 0; k < 8; ++k) aa[k] = aan[k];
          tw = (tw == 2) ? 0 : tw + 1;
          BARRIER();
        }
      }
    } else {
      // ---- gen phase first: tiles TT-3-s while >= F
      if (s <= TT - 3 && (TT - 3 - s) >= F){
        // gen phase nonempty => t0 = TT-2 > F => prologue was GEN (weights loaded)
        const int tg0 = TT - 3;
        #pragma unroll
        for (int k = 0; k < 8; ++k) aa[k] = aLDS[tg0 * AA + k];
        for (; s <= TT - 3 && (TT - 3 - s) >= F; ++s){
          const int tgi = TT - 3 - s;
          if (tgi > F){
            #pragma unroll
            for (int k = 0; k < 8; ++k) aan[k] = aLDS[(tgi - 1) * AA + k];
          }
          GENT(tw);
          #pragma unroll
          for (int k = 0; k < 8; ++k) aa[k] = aan[k];
          tw = (tw == 2) ? 0 : tw + 1;
          BARRIER();
        }
      }
      // ---- stream phase: descending tiles (TT-3-s)..0, all < F
      if (s <= TT - 3){
        const int tc0 = TT - 3 - s;
        uint4 A, B, C;
        A = *(const uint4*)(gbh + (size_t)tc0 * tsh);
        if (tc0 - 1 >= 0) B = *(const uint4*)(gbh + (size_t)(tc0 - 1) * tsh);
        if (tc0 - 2 >= 0) C = *(const uint4*)(gbh + (size_t)(tc0 - 2) * tsh);
        int tnext = tc0 - 3, par = 0;
        for (; s <= TT - 3; ++s){
          if (par == 0){
            STORE_H8(tw, A);
            if (tnext >= 0){ A = *(const uint4*)(gbh + (size_t)tnext * tsh); --tnext; }
          } else if (par == 1){
            STORE_H8(tw, B);
            if (tnext >= 0){ B = *(const uint4*)(gbh + (size_t)tnext * tsh); --tnext; }
          } else {
            STORE_H8(tw, C);
            if (tnext >= 0){ C = *(const uint4*)(gbh + (size_t)tnext * tsh); --tnext; }
          }
          par = (par == 2) ? 0 : par + 1;
          tw = (tw == 2) ? 0 : tw + 1;
          BARRIER();
        }
      }
    }
    // tail: final consumer iteration produces nothing
    for (; s <= TT - 2; ++s) BARRIER();
  } else if (is_fwd){
    // ==================== FORWARD CONSUMERS ====================
    const int wb16 = __builtin_amdgcn_readfirstlane(w * 16);
    float u = __expf(slx[b * SS + lane] + il[lane]);     // unnormalized alpha_0
    float c = __builtin_amdgcn_rcpf(wave_sum_dpp(u));
    if (w == 0) alpha[b * SS + lane] = u * c;
    float slxn = slx[(BB + b) * SS + lane];              // slx[t=1]
    float elxc = 0.f;
    BARRIER();
    int ts = 0;
    for (int s = 0; s < TT - 1; ++s){
      if (s > 0){
        const int fs = (s - 1) & 1;
        float S = (fpart[fs][0][lane] + fpart[fs][1][lane])
                + (fpart[fs][2][lane] + fpart[fs][3][lane]);
        u = elxc * fmaf(c, S, SEPS);                     // alpha_s (unnormalized)
        c = __builtin_amdgcn_rcpf(wave_sum_dpp(u));      // off critical path (DPP)
        if (w == 0) alpha[(s * BB + b) * SS + lane] = u * c;
      }
      float va;
      if (s < F){
        va = u;                                          // streamed: rowsum == 1
      } else {
        float rs = ((rsp[ts][0][lane] + rsp[ts][1][lane]) + (rsp[ts][2][lane] + rsp[ts][3][lane]))
                 + ((rsp[ts][4][lane] + rsp[ts][5][lane]) + (rsp[ts][6][lane] + rsp[ts][7][lane]));
        va = u * __builtin_amdgcn_rcpf(rs);              // u_i / rowsum_i (lane = i)
      }
      const float* __restrict__ tp = &tile[ts][0];
      float a0 = 0.f, a1 = 0.f, a2 = 0.f, a3 = 0.f;
      #pragma unroll
      for (int r = 0; r < 16; r += 4){
        a0 = fmaf(readlane_f(va, wb16 + r    ), tp[(wb16 + r    ) * TS + lane], a0);
        a1 = fmaf(readlane_f(va, wb16 + r + 1), tp[(wb16 + r + 1) * TS + lane], a1);
        a2 = fmaf(readlane_f(va, wb16 + r + 2), tp[(wb16 + r + 2) * TS + lane], a2);
        a3 = fmaf(readlane_f(va, wb16 + r + 3), tp[(wb16 + r + 3) * TS + lane], a3);
      }
      fpart[s & 1][w][lane] = (a0 + a1) + (a2 + a3);
      elxc = __expf(slxn);                               // for step s+1, off path
      if (s + 2 <= TT - 1) slxn = slx[((s + 2) * BB + b) * SS + lane];
      ts = (ts == 2) ? 0 : ts + 1;
      BARRIER();
    }
    { // epilogue: alpha_{T-1}
      const int fs = (TT - 2) & 1;
      float S = (fpart[fs][0][lane] + fpart[fs][1][lane])
              + (fpart[fs][2][lane] + fpart[fs][3][lane]);
      u = elxc * fmaf(c, S, SEPS);
      c = __builtin_amdgcn_rcpf(wave_sum_dpp(u));
      if (w == 0) alpha[((TT - 1) * BB + b) * SS + lane] = u * c;
    }
  } else {
    // ==================== BACKWARD CONSUMERS ====================
    // breg kept in relative form (per-(t,b) shift drops in the q_z softmax);
    // renormalized by W each step so all values stay in [ln EPS, ~0].
    const int wb16 = __builtin_amdgcn_readfirstlane(w * 16);
    const int sgen = TT - 1 - F;   // steps s > sgen use streamed prev-tile
    float breg = 0.f, rWc = 1.f;
    if (w == 0) log_beta[((TT - 1) * BB + b) * SS + lane] = 0.f;
    float slxc = slx[((TT - 1) * BB + b) * SS + lane];
    float mprev = 1.f;
    BARRIER();
    int ts = 0, pts = 2;
    for (int s = 0; s < TT - 1; ++s){
      if (s > 0){
        const int fs = (s - 1) & 1;
        float eh = (fpart[fs][0][lane] + fpart[fs][1][lane])
                 + (fpart[fs][2][lane] + fpart[fs][3][lane]);
        float ehn;
        if (s > sgen){
          ehn = eh;                                      // streamed: rowsum == 1
        } else {
          float rsv = ((rsp[pts][0][lane] + rsp[pts][1][lane]) + (rsp[pts][2][lane] + rsp[pts][3][lane]))
                    + ((rsp[pts][4][lane] + rsp[pts][5][lane]) + (rsp[pts][6][lane] + rsp[pts][7][lane]));
          ehn = eh * __builtin_amdgcn_rcpf(rsv);
        }
        // v = log( sum_j (tr_ij/rowsum_i) * wgt_j / W + EPS )  (shift-relative LSE)
        float v = __logf(fmaf(ehn, rWc, EPSF));
        breg = (mprev == 1.0f) ? v : 0.0f;
        if (w == 0) log_beta[((TT - 1 - s) * BB + b) * SS + lane] = breg;
      }
      float wgt = __expf(slxc + breg);                   // lane = j
      float W = wave_sum_dpp(wgt);                       // overlaps matvec (VALU)
      rWc = __builtin_amdgcn_rcpf(W);                    // consumed next iter
      const float* __restrict__ tp = &tile[ts][lane * TS + wb16];
      float4 e0 = *(const float4*)(tp);
      float4 e1 = *(const float4*)(tp + 4);
      float4 e2 = *(const float4*)(tp + 8);
      float4 e3 = *(const float4*)(tp + 12);
      float a0 = 0.f, a1 = 0.f, a2 = 0.f, a3 = 0.f;
      a0 = fmaf(readlane_f(wgt, wb16 + 0),  e0.x, a0);
      a1 = fmaf(readlane_f(wgt, wb16 + 1),  e0.y, a1);
      a2 = fmaf(readlane_f(wgt, wb16 + 2),  e0.z, a2);
      a3 = fmaf(readlane_f(wgt, wb16 + 3),  e0.w, a3);
      a0 = fmaf(readlane_f(wgt, wb16 + 4),  e1.x, a0);
      a1 = fmaf(readlane_f(wgt, wb16 + 5),  e1.y, a1);
      a2 = fmaf(readlane_f(wgt, wb16 + 6),  e1.z, a2);
      a3 = fmaf(readlane_f(wgt, wb16 + 7),  e1.w, a3);
      a0 = fmaf(readlane_f(wgt, wb16 + 8),  e2.x, a0);
      a1 = fmaf(readlane_f(wgt, wb16 + 9),  e2.y, a1);
      a2 = fmaf(readlane_f(wgt, wb16 + 10), e2.z, a2);
      a3 = fmaf(readlane_f(wgt, wb16 + 11), e2.w, a3);
      a0 = fmaf(readlane_f(wgt, wb16 + 12), e3.x, a0);
      a1 = fmaf(readlane_f(wgt, wb16 + 13), e3.y, a1);
      a2 = fmaf(readlane_f(wgt, wb16 + 14), e3.z, a2);
      a3 = fmaf(readlane_f(wgt, wb16 + 15), e3.w, a3);
      fpart[s & 1][w][lane] = (a0 + a1) + (a2 + a3);
      mprev = mLDS[TT - 1 - s];
      if (s <= TT - 3) slxc = slx[((TT - 2 - s) * BB + b) * SS + lane];
      pts = ts; ts = (ts == 2) ? 0 : ts + 1;
      BARRIER();
    }
    { // epilogue: breg_0 (tile t=0 streamed whenever F > 0)
      const int fs = (TT - 2) & 1;
      float eh = (fpart[fs][0][lane] + fpart[fs][1][lane])
               + (fpart[fs][2][lane] + fpart[fs][3][lane]);
      float ehn;
      if (F > 0){
        ehn = eh;
      } else {
        float rsv = ((rsp[pts][0][lane] + rsp[pts][1][lane]) + (rsp[pts][2][lane] + rsp[pts][3][lane]))
                  + ((rsp[pts][4][lane] + rsp[pts][5][lane]) + (rsp[pts][6][lane] + rsp[pts][7][lane]));
        ehn = eh * __builtin_amdgcn_rcpf(rsv);
      }
      float v = __logf(fmaf(ehn, rWc, EPSF));
      breg = (mprev == 1.0f) ? v : 0.0f;
      if (w == 0) log_beta[b * SS + lane] = breg;
    }
  }
}

// --- kernel 3: q_z = softmax(log(alpha+EPS) + log_beta) over states
__global__ __launch_bounds__(256) void qz_kernel(
    const float* __restrict__ alpha, const float* __restrict__ log_beta,
    float* __restrict__ out){
  const int lane = threadIdx.x & 63;
  const int w = threadIdx.x >> 6;
  const int row = blockIdx.x * 4 + w;
  float v = __logf(alpha[row * SS + lane] + EPSF) + log_beta[row * SS + lane];
  float mx = wave_max(v);
  float e = __expf(v - mx);
  float sm = wave_sum(e);
  out[row * SS + lane] = e * __builtin_amdgcn_rcpf(sm);
}

extern "C" void kernel_launch(void* const* d_in, const int* in_sizes, int n_in,
                              void* d_out, int out_size, void* d_ws, size_t ws_size,
                              hipStream_t stream){
  const float* x      = (const float*)d_in[0];
  const float* a      = (const float*)d_in[1];
  const float* mask   = (const float*)d_in[2];
  const float* mu     = (const float*)d_in[3];
  const float* logv   = (const float*)d_in[4];
  const float* il     = (const float*)d_in[5];
  const float* w_base = (const float*)d_in[6];
  const float* w_act  = (const float*)d_in[7];
  float* out = (float*)d_out;

  float* ws = (float*)d_ws;
  const size_t TBS = (size_t)TT * BB * SS;
  float* iv       = ws;               // 2048 (+ cs, padded to 4096)
  float* cs       = ws + 2048;
  float* slx      = ws + 4096;        // TBS
  float* alpha    = slx + TBS;        // TBS
  float* log_beta = alpha + TBS;      // TBS
  unsigned short* trans = (unsigned short*)(log_beta + TBS); // F fp16 t-slices

  // Adaptive precompute depth: as many of the 511 transition t-slices as the
  // workspace can hold (each slice = BB*SS*SS halves = 256 KB).
  const long long base_bytes = ((long long)4096 + 3 * (long long)TBS) * 4;
  const long long slice_bytes = (long long)BB * SS * SS * 2;
  long long availb = (long long)ws_size - base_bytes;
  int F = 0;
  if (availb > 0){
    long long f = availb / slice_bytes;
    F = (f > (TT - 1)) ? (TT - 1) : (int)f;
  }
  if (F < 8) F = 0;   // not worth the stream prologue edge cases

  prep_kernel<<<8, 256, 0, stream>>>(logv, iv, cs);
  logpx_kernel<<<TT * BB / 4, 256, 0, stream>>>(x, mu, iv, cs, slx);
  if (F > 0)
    trans_kernel<<<512, 512, 0, stream>>>(a, w_base, w_act, trans, F);
  scan_hybrid_kernel<<<2 * BB, 768, 0, stream>>>(slx, mask, il, a, w_base, w_act,
                                                 trans, F, alpha, log_beta);
  qz_kernel<<<TT * BB / 4, 256, 0, stream>>>(alpha, log_beta, out);
}